// Round 10
// baseline (177.505 us; speedup 1.0000x reference)
//
#include <hip/hip_runtime.h>

#define N_NODES 50000
#define N_EDGES 800000
#define F_IN    64
#define H_DIM   128
#define N_GRAPHS 512
#define LN_EPS  1e-5f
#define CAP     64          // max in-degree bucket capacity (Poisson(16): P(deg>=64) ~ 1e-20)
#define NBINS   196         // ceil(50000/256) -- bin = dst >> 8
#define BINCAP  5120        // edges per bin region
#define CHUNK   2048        // edges per partition block

typedef short  short8 __attribute__((ext_vector_type(8)));
typedef float  f32x4  __attribute__((ext_vector_type(4)));
typedef unsigned short u16;
typedef unsigned int   u32;

__device__ __forceinline__ float bf2f(u16 u) {
    u32 b = ((u32)u) << 16;
    return __builtin_bit_cast(float, b);
}
__device__ __forceinline__ u16 f2bf(float f) {   // round-to-nearest-even
    u32 b = __builtin_bit_cast(u32, f);
    return (u16)((b + 0x7FFFu + ((b >> 16) & 1u)) >> 16);
}

// ---------------------------------------------------------------------------
// pack weights into MFMA B-fragment order, bf16 (device helper).
__device__ __forceinline__ void packw_body(const float* __restrict__ Wl,
                                           const float* __restrict__ Wr,
                                           const float* __restrict__ Rw,
                                           u16* __restrict__ out, int K, int tid) {
    int lane = tid & 63;
    int tile = (tid >> 6) & 7;
    int kstep = tid >> 9;
    int col = tile * 16 + (lane & 15);
    short8 o;
    #pragma unroll
    for (int e = 0; e < 8; ++e) {
        int k = kstep * 32 + (lane >> 4) * 8 + e;
        float v = (k < K) ? Wl[(size_t)k * H_DIM + col]
                          : (Wr[(size_t)(k - K) * H_DIM + col] + Rw[(size_t)(k - K) * H_DIM + col]);
        o[e] = (short)f2bf(v);
    }
    *reinterpret_cast<short8*>(&out[(size_t)tid * 8]) = o;
}

// ---------------------------------------------------------------------------
// fused prep: cvt(x->bf16) | bias-combine+binCnt-zero | packw0 | packw1 | bounds
#define CVT_BLOCKS   3125
#define PW0_BLOCKS   8
#define PW1_BLOCKS   16
#define BND_BLOCKS   196
__launch_bounds__(256)
__global__ void prep_kernel(const float* __restrict__ x, u16* __restrict__ xbf,
                            const float* __restrict__ l0b, const float* __restrict__ r0b,
                            const float* __restrict__ l1b, const float* __restrict__ r1b,
                            float* __restrict__ bcc, int* __restrict__ binCnt,
                            const float* __restrict__ Wl0, const float* __restrict__ Wr0,
                            const float* __restrict__ Rw0, u16* __restrict__ W0p,
                            const float* __restrict__ Wl1, const float* __restrict__ Wr1,
                            const float* __restrict__ Rw1, u16* __restrict__ W1p,
                            const int* __restrict__ batch, int* __restrict__ gstart) {
    const int b = blockIdx.x;
    const int tid = threadIdx.x;
    if (b < CVT_BLOCKS) {
        int i = b * 256 + tid;
        float4 v = reinterpret_cast<const float4*>(x)[i];
        ushort4 o;
        o.x = f2bf(v.x); o.y = f2bf(v.y); o.z = f2bf(v.z); o.w = f2bf(v.w);
        reinterpret_cast<ushort4*>(xbf)[i] = o;
    } else if (b == CVT_BLOCKS) {
        if (tid < 128) {
            bcc[tid]       = l0b[tid] + r0b[tid];
            bcc[128 + tid] = l1b[tid] + r1b[tid];
            binCnt[tid] = 0;
            binCnt[128 + tid] = 0;
        }
    } else if (b < CVT_BLOCKS + 1 + PW0_BLOCKS) {
        packw_body(Wl0, Wr0, Rw0, W0p, F_IN, (b - CVT_BLOCKS - 1) * 256 + tid);
    } else if (b < CVT_BLOCKS + 1 + PW0_BLOCKS + PW1_BLOCKS) {
        packw_body(Wl1, Wr1, Rw1, W1p, H_DIM, (b - CVT_BLOCKS - 1 - PW0_BLOCKS) * 256 + tid);
    } else {
        int i = (b - CVT_BLOCKS - 1 - PW0_BLOCKS - PW1_BLOCKS) * 256 + tid;
        if (i >= N_NODES) return;
        int bb = batch[i];
        int prev = (i == 0) ? -1 : batch[i - 1];
        for (int g = prev + 1; g <= bb; ++g) gstart[g] = i;
        if (i == N_NODES - 1)
            for (int g = bb + 1; g <= N_GRAPHS; ++g) gstart[g] = N_NODES;
    }
}

// ---------------------------------------------------------------------------
// Phase 1: partition edges into NBINS coarse bins (bin = dst>>8).
#define EPT (CHUNK / 256)
__launch_bounds__(256)
__global__ void partition_kernel(const int* __restrict__ src, const int* __restrict__ dst,
                                 int* __restrict__ binCnt, ushort2* __restrict__ binned) {
    __shared__ ushort2 lbuf[CHUNK];
    __shared__ int sHist[256];
    __shared__ int sScan[256];
    __shared__ int sCur[256];
    __shared__ int sGBase[256];
    __shared__ int sWS[4];
    const int tid = threadIdx.x;
    const int base = blockIdx.x * CHUNK;
    const int cnt = min(CHUNK, N_EDGES - base);

    int es[EPT], ed[EPT], nb[EPT];
    #pragma unroll
    for (int i = 0; i < EPT; ++i) {
        int idx = base + i * 256 + tid;
        if (idx < N_EDGES) { es[i] = src[idx]; ed[i] = dst[idx]; nb[i] = ed[i] >> 8; }
        else nb[i] = -1;
    }
    sHist[tid] = 0;
    __syncthreads();
    #pragma unroll
    for (int i = 0; i < EPT; ++i) if (nb[i] >= 0) atomicAdd(&sHist[nb[i]], 1);
    __syncthreads();

    int v = sHist[tid];
    int pv = v;
    #pragma unroll
    for (int off = 1; off < 64; off <<= 1) {
        int t = __shfl_up(pv, off, 64);
        if ((tid & 63) >= off) pv += t;
    }
    if ((tid & 63) == 63) sWS[tid >> 6] = pv;
    __syncthreads();
    int wadd = 0;
    #pragma unroll
    for (int wg = 0; wg < 4; ++wg) if (wg < (tid >> 6)) wadd += sWS[wg];
    int excl = pv + wadd - v;
    sScan[tid] = excl;
    sCur[tid]  = excl;
    if (tid < NBINS && v > 0)
        sGBase[tid] = atomicAdd(&binCnt[tid], v);
    __syncthreads();

    #pragma unroll
    for (int i = 0; i < EPT; ++i) {
        if (nb[i] >= 0) {
            int p = atomicAdd(&sCur[nb[i]], 1);
            ushort2 t; t.x = (u16)es[i]; t.y = (u16)ed[i];
            lbuf[p] = t;
        }
    }
    __syncthreads();

    for (int t = tid; t < cnt; t += 256) {
        ushort2 e = lbuf[t];
        int b = e.y >> 8;
        int slot = sGBase[b] + (t - sScan[b]);
        if (slot < BINCAP) binned[(size_t)b * BINCAP + slot] = e;
    }
}

// ---------------------------------------------------------------------------
// Phase 2: per-bin bucket fill (u16 bucket); per-node cursors in LDS.
__launch_bounds__(256)
__global__ void fillbin_kernel(const ushort2* __restrict__ binned, const int* __restrict__ binCnt,
                               u16* __restrict__ bucket, int* __restrict__ degv) {
    __shared__ int lcur[256];
    const int b = blockIdx.x;
    const int tid = threadIdx.x;
    const int nodeBase = b << 8;
    lcur[tid] = 0;
    __syncthreads();
    int cnt = binCnt[b];
    if (cnt > BINCAP) cnt = BINCAP;
    const ushort2* be = &binned[(size_t)b * BINCAP];
    for (int t = tid; t < cnt; t += 256) {
        ushort2 e = be[t];
        int d = e.y;
        int pos = atomicAdd(&lcur[d & 255], 1);
        if (pos < CAP) bucket[(size_t)d * CAP + pos] = e.x;
    }
    __syncthreads();
    int node = nodeBase + tid;
    if (node < N_NODES) degv[node] = lcur[tid];
}

// ---------------------------------------------------------------------------
// per-node neighbor-sum gather (16-deep ILP, SGPR row bases). Returns sums.
template <int K>
__device__ __forceinline__ void gather_node(const u16* __restrict__ h,
                                            const u16* __restrict__ bk,
                                            int dgc, int lane, int lane2,
                                            float& r0, float& r1) {
    float a0[8], a1[8];
    #pragma unroll
    for (int u = 0; u < 8; ++u) { a0[u] = 0.f; a1[u] = 0.f; }
    int e = 0;
    for (; e + 16 <= dgc; e += 16) {
        int4 qa = *reinterpret_cast<const int4*>(&bk[e]);
        int4 qb = *reinterpret_cast<const int4*>(&bk[e + 8]);
        u32 p[8];
        p[0] = (u32)__builtin_amdgcn_readfirstlane(qa.x);
        p[1] = (u32)__builtin_amdgcn_readfirstlane(qa.y);
        p[2] = (u32)__builtin_amdgcn_readfirstlane(qa.z);
        p[3] = (u32)__builtin_amdgcn_readfirstlane(qa.w);
        p[4] = (u32)__builtin_amdgcn_readfirstlane(qb.x);
        p[5] = (u32)__builtin_amdgcn_readfirstlane(qb.y);
        p[6] = (u32)__builtin_amdgcn_readfirstlane(qb.z);
        p[7] = (u32)__builtin_amdgcn_readfirstlane(qb.w);
        if constexpr (K == 128) {
            u32 w[16];
            #pragma unroll
            for (int u = 0; u < 8; ++u) {
                w[2 * u]     = *reinterpret_cast<const u32*>(h + (size_t)(p[u] & 0xFFFFu) * K + lane2);
                w[2 * u + 1] = *reinterpret_cast<const u32*>(h + (size_t)(p[u] >> 16) * K + lane2);
            }
            #pragma unroll
            for (int u = 0; u < 8; ++u) {
                a0[u] += bf2f((u16)w[u]);        a1[u] += bf2f((u16)(w[u] >> 16));
                a0[u] += bf2f((u16)w[u + 8]);    a1[u] += bf2f((u16)(w[u + 8] >> 16));
            }
        } else {
            u16 w[16];
            #pragma unroll
            for (int u = 0; u < 8; ++u) {
                w[2 * u]     = *(h + (size_t)(p[u] & 0xFFFFu) * K + lane);
                w[2 * u + 1] = *(h + (size_t)(p[u] >> 16) * K + lane);
            }
            #pragma unroll
            for (int u = 0; u < 8; ++u) { a0[u] += bf2f(w[u]); a0[u] += bf2f(w[u + 8]); }
        }
    }
    for (; e + 8 <= dgc; e += 8) {
        int4 qa = *reinterpret_cast<const int4*>(&bk[e]);
        u32 p[4];
        p[0] = (u32)__builtin_amdgcn_readfirstlane(qa.x);
        p[1] = (u32)__builtin_amdgcn_readfirstlane(qa.y);
        p[2] = (u32)__builtin_amdgcn_readfirstlane(qa.z);
        p[3] = (u32)__builtin_amdgcn_readfirstlane(qa.w);
        if constexpr (K == 128) {
            u32 w[8];
            #pragma unroll
            for (int u = 0; u < 4; ++u) {
                w[2 * u]     = *reinterpret_cast<const u32*>(h + (size_t)(p[u] & 0xFFFFu) * K + lane2);
                w[2 * u + 1] = *reinterpret_cast<const u32*>(h + (size_t)(p[u] >> 16) * K + lane2);
            }
            #pragma unroll
            for (int u = 0; u < 8; ++u) { a0[u] += bf2f((u16)w[u]); a1[u] += bf2f((u16)(w[u] >> 16)); }
        } else {
            u16 w[8];
            #pragma unroll
            for (int u = 0; u < 4; ++u) {
                w[2 * u]     = *(h + (size_t)(p[u] & 0xFFFFu) * K + lane);
                w[2 * u + 1] = *(h + (size_t)(p[u] >> 16) * K + lane);
            }
            #pragma unroll
            for (int u = 0; u < 8; ++u) a0[u] += bf2f(w[u]);
        }
    }
    {
        int rem = dgc - e;
        #pragma unroll
        for (int u = 0; u < 7; ++u) {
            if (u < rem) {
                int s = __builtin_amdgcn_readfirstlane((int)bk[e + u]);
                if constexpr (K == 128) {
                    u32 w = *reinterpret_cast<const u32*>(h + (size_t)s * K + lane2);
                    a0[u] += bf2f((u16)w);
                    a1[u] += bf2f((u16)(w >> 16));
                } else {
                    a0[u] += bf2f(*(h + (size_t)s * K + lane));
                }
            }
        }
    }
    r0 = (((a0[0] + a0[1]) + (a0[2] + a0[3])) + ((a0[4] + a0[5]) + (a0[6] + a0[7])));
    if constexpr (K == 128)
        r1 = (((a1[0] + a1[1]) + (a1[2] + a1[3])) + ((a1[4] + a1[5]) + (a1[6] + a1[7])));
}

// ---------------------------------------------------------------------------
// FUSED gather + MFMA layer: block = 4 waves, 64 nodes.
//   Phase A: all threads stage hin half to LDS; wave w gathers its 16 nodes'
//            neighbor means and writes bf16 directly into the swizzled A-tile.
//   Phase B: MFMA over [agg | hin] @ Wpack, +bias, LayerNorm, output.
template <int K, bool RELU, bool FINAL>
__launch_bounds__(256)
__global__ void fused_layer_kernel(const u16* __restrict__ hbf,     // [N,K]
                                   const u16* __restrict__ bucket,  // [N,CAP]
                                   const int* __restrict__ degv,    // [N]
                                   const u16* __restrict__ Wpack,
                                   const float* __restrict__ bc,
                                   const float* __restrict__ ln_g,
                                   const float* __restrict__ ln_b,
                                   const float* __restrict__ ow,
                                   u16* __restrict__ hout,
                                   float* __restrict__ sout) {
    constexpr int K2   = 2 * K;
    constexpr int NKS  = K2 / 32;
    constexpr int ROWB = K2 * 2;      // bytes per LDS row
    constexpr int HCH  = K * 2 / 16;  // 16B chunks per row (hin half)
    __shared__ __align__(16) char sA[64 * ROWB];

    const int tid  = threadIdx.x;
    const int lane = tid & 63;
    const int wid  = tid >> 6;
    const int base = blockIdx.x * 64;
    const int lane2 = lane * 2;

    // ---- Phase A1: stage hin half (block-wide, coalesced 16B) ----
    for (int c = tid; c < 64 * HCH; c += 256) {
        int row = c / HCH, ch = c % HCH;
        int rg = base + row; if (rg >= N_NODES) rg = N_NODES - 1;
        float4 v = *reinterpret_cast<const float4*>(&hbf[(size_t)rg * K + ch * 8]);
        *reinterpret_cast<float4*>(&sA[row * ROWB + (((HCH + ch) * 16) ^ ((row & 7) << 4))]) = v;
    }

    // ---- Phase A2: gather agg half (wave-per-16-nodes, LDS-direct write) ----
    #pragma unroll 1
    for (int n = 0; n < 16; ++n) {
        const int row = wid * 16 + n;
        const int node = base + row;
        float s0 = 0.f, s1 = 0.f;
        if (node < N_NODES) {
            int dg = degv[node];
            int dgc = dg > CAP ? CAP : dg;
            gather_node<K>(hbf, &bucket[(size_t)node * CAP], dgc, lane, lane2, s0, s1);
            const float invd = 1.0f / fmaxf((float)dg, 1.0f);
            s0 *= invd; s1 *= invd;
        }
        if constexpr (K == 128) {
            u32 o = (u32)f2bf(s0) | ((u32)f2bf(s1) << 16);
            *reinterpret_cast<u32*>(&sA[row * ROWB + ((lane * 4) ^ ((row & 7) << 4))]) = o;
        } else {
            *reinterpret_cast<u16*>(&sA[row * ROWB + ((lane * 2) ^ ((row & 7) << 4))]) = f2bf(s0);
        }
    }
    __syncthreads();

    // ---- Phase B: MFMA accumulate ----
    f32x4 acc[8];
    #pragma unroll
    for (int t = 0; t < 8; ++t) acc[t] = (f32x4){0.f, 0.f, 0.f, 0.f};

    const int arow = lane & 15;
    const int kg   = lane >> 4;
    const int lrow = wid * 16 + arow;
    #pragma unroll
    for (int ks = 0; ks < NKS; ++ks) {
        short8 af = *reinterpret_cast<const short8*>(
            &sA[lrow * ROWB + (((ks * 64 + kg * 16)) ^ ((lrow & 7) << 4))]);
        #pragma unroll
        for (int t = 0; t < 8; ++t) {
            short8 bf = *reinterpret_cast<const short8*>(&Wpack[(size_t)((ks * 8 + t) * 64 + lane) * 8]);
            acc[t] = __builtin_amdgcn_mfma_f32_16x16x32_bf16(af, bf, acc[t], 0, 0, 0);
        }
    }

    // ---- epilogue: +bias, LayerNorm per row, output ----
    const int col0 = lane & 15;
    const int g    = lane >> 4;

    float lg[8], lb[8], wv[8];
    #pragma unroll
    for (int t = 0; t < 8; ++t) {
        const int col = col0 + 16 * t;
        const float cb = bc[col];
        lg[t] = ln_g[col]; lb[t] = ln_b[col];
        if (FINAL) wv[t] = ow[col];
        #pragma unroll
        for (int r = 0; r < 4; ++r) acc[t][r] += cb;
    }

    #pragma unroll
    for (int r = 0; r < 4; ++r) {
        float s = 0.f, q = 0.f;
        #pragma unroll
        for (int t = 0; t < 8; ++t) { s += acc[t][r]; q += acc[t][r] * acc[t][r]; }
        #pragma unroll
        for (int off = 8; off > 0; off >>= 1) {
            s += __shfl_xor(s, off, 64);
            q += __shfl_xor(q, off, 64);
        }
        const float mean = s * (1.0f / H_DIM);
        const float var  = q * (1.0f / H_DIM) - mean * mean;
        const float rstd = rsqrtf(var + LN_EPS);
        const int row = base + wid * 16 + g * 4 + r;

        if (FINAL) {
            float dot = 0.f;
            #pragma unroll
            for (int t = 0; t < 8; ++t) {
                float o = (acc[t][r] - mean) * rstd * lg[t] + lb[t];
                dot += o * wv[t];
            }
            #pragma unroll
            for (int off = 8; off > 0; off >>= 1) dot += __shfl_xor(dot, off, 64);
            if (col0 == 0 && row < N_NODES) sout[row] = dot;
        } else {
            if (row < N_NODES) {
                #pragma unroll
                for (int t = 0; t < 8; ++t) {
                    float o = (acc[t][r] - mean) * rstd * lg[t] + lb[t];
                    if (RELU) o = fmaxf(o, 0.f);
                    hout[(size_t)row * H_DIM + col0 + 16 * t] = f2bf(o);
                }
            }
        }
    }
}

// ---------------------------------------------------------------------------
__device__ __forceinline__ float waveReduceSum(float v) {
    #pragma unroll
    for (int off = 32; off > 0; off >>= 1) v += __shfl_xor(v, off, 64);
    return v;
}

__global__ void graph_mean_kernel(const float* __restrict__ s, const int* __restrict__ start,
                                  const float* __restrict__ ob, float* __restrict__ out) {
    const int g = blockIdx.x;
    const int lane = threadIdx.x;
    const int a = start[g], b = start[g + 1];
    float sum = 0.f;
    for (int i = a + lane; i < b; i += 64) sum += s[i];
    sum = waveReduceSum(sum);
    if (lane == 0) out[g] = sum / fmaxf((float)(b - a), 1.0f) + ob[0];
}

// ---------------------------------------------------------------------------
static inline size_t align256(size_t x) { return (x + 255) & ~(size_t)255; }

extern "C" void kernel_launch(void* const* d_in, const int* in_sizes, int n_in,
                              void* d_out, int out_size, void* d_ws, size_t ws_size,
                              hipStream_t stream) {
    const float* x        = (const float*)d_in[0];
    const int*   eidx     = (const int*)d_in[1];
    const int*   batch    = (const int*)d_in[2];
    const float* lin_l0_w = (const float*)d_in[3];
    const float* lin_l0_b = (const float*)d_in[4];
    const float* lin_r0_w = (const float*)d_in[5];
    const float* res0_w   = (const float*)d_in[6];
    const float* res0_b   = (const float*)d_in[7];
    const float* ln0_g    = (const float*)d_in[8];
    const float* ln0_b    = (const float*)d_in[9];
    const float* lin_l1_w = (const float*)d_in[10];
    const float* lin_l1_b = (const float*)d_in[11];
    const float* lin_r1_w = (const float*)d_in[12];
    const float* res1_w   = (const float*)d_in[13];
    const float* res1_b   = (const float*)d_in[14];
    const float* ln1_g    = (const float*)d_in[15];
    const float* ln1_b    = (const float*)d_in[16];
    const float* out_w    = (const float*)d_in[17];
    const float* out_b    = (const float*)d_in[18];
    float* out = (float*)d_out;

    const int* src = eidx;
    const int* dst = eidx + N_EDGES;

    // workspace layout
    char* p = (char*)d_ws;
    int*     binCnt = (int*)p;     p += align256(256 * 4);
    ushort2* binned = (ushort2*)p; p += align256((size_t)NBINS * BINCAP * 4);
    int*     degv   = (int*)p;     p += align256((size_t)N_NODES * 4);
    u16*     bucket = (u16*)p;     p += align256((size_t)N_NODES * CAP * 2);
    int*     gstart = (int*)p;     p += align256((size_t)(N_GRAPHS + 1) * 4);
    u16*     xbf    = (u16*)p;     p += align256((size_t)N_NODES * F_IN * 2);
    u16*     h0bf   = (u16*)p;     p += align256((size_t)N_NODES * H_DIM * 2);
    float*   snode  = (float*)p;   p += align256((size_t)N_NODES * 4);
    u16*     W0p    = (u16*)p;     p += align256((size_t)(2 * F_IN) * H_DIM * 2);
    u16*     W1p    = (u16*)p;     p += align256((size_t)(2 * H_DIM) * H_DIM * 2);
    float*   bcc    = (float*)p;   p += align256(256 * 4);

    // fused prep (cvt + bias/binCnt + packw0 + packw1 + bounds)
    prep_kernel<<<CVT_BLOCKS + 1 + PW0_BLOCKS + PW1_BLOCKS + BND_BLOCKS, 256, 0, stream>>>(
        x, xbf, lin_l0_b, res0_b, lin_l1_b, res1_b, bcc, binCnt,
        lin_l0_w, lin_r0_w, res0_w, W0p, lin_l1_w, lin_r1_w, res1_w, W1p,
        batch, gstart);

    // two-phase edge bucketing
    partition_kernel<<<(N_EDGES + CHUNK - 1) / CHUNK, 256, 0, stream>>>(src, dst, binCnt, binned);
    fillbin_kernel<<<NBINS, 256, 0, stream>>>(binned, binCnt, bucket, degv);

    const int nTiles = (N_NODES + 63) / 64;

    // layer 0: fused gather+GEMM+LN+ReLU
    fused_layer_kernel<F_IN, true, false><<<nTiles, 256, 0, stream>>>(
        xbf, bucket, degv, W0p, bcc, ln0_g, ln0_b, nullptr, h0bf, nullptr);

    // layer 1: fused gather+GEMM+LN+out_w dot
    fused_layer_kernel<H_DIM, false, true><<<nTiles, 256, 0, stream>>>(
        h0bf, bucket, degv, W1p, bcc + 128, ln1_g, ln1_b, out_w, nullptr, snode);

    // per-graph mean + bias
    graph_mean_kernel<<<N_GRAPHS, 64, 0, stream>>>(snode, gstart, out_b, out);
}

// Round 11
// 127.560 us; speedup vs baseline: 1.3915x; 1.3915x over previous
//
#include <hip/hip_runtime.h>

#define N_NODES 50000
#define N_EDGES 800000
#define F_IN    64
#define H_DIM   128
#define N_GRAPHS 512
#define LN_EPS  1e-5f
#define CAP     64          // max in-degree bucket capacity (Poisson(16): P(deg>=64) ~ 1e-20)
#define NBINS   196         // ceil(50000/256) -- bin = dst >> 8
#define BINCAP  5120        // edges per bin region
#define CHUNK   2048        // edges per partition block

typedef short  short8 __attribute__((ext_vector_type(8)));
typedef float  f32x4  __attribute__((ext_vector_type(4)));
typedef unsigned short u16;
typedef unsigned int   u32;

__device__ __forceinline__ float bf2f(u16 u) {
    u32 b = ((u32)u) << 16;
    return __builtin_bit_cast(float, b);
}
__device__ __forceinline__ u16 f2bf(float f) {   // round-to-nearest-even
    u32 b = __builtin_bit_cast(u32, f);
    return (u16)((b + 0x7FFFu + ((b >> 16) & 1u)) >> 16);
}

// ---------------------------------------------------------------------------
// pack weights into MFMA B-fragment order, bf16 (device helper).
__device__ __forceinline__ void packw_body(const float* __restrict__ Wl,
                                           const float* __restrict__ Wr,
                                           const float* __restrict__ Rw,
                                           u16* __restrict__ out, int K, int tid) {
    int lane = tid & 63;
    int tile = (tid >> 6) & 7;
    int kstep = tid >> 9;
    int col = tile * 16 + (lane & 15);
    short8 o;
    #pragma unroll
    for (int e = 0; e < 8; ++e) {
        int k = kstep * 32 + (lane >> 4) * 8 + e;
        float v = (k < K) ? Wl[(size_t)k * H_DIM + col]
                          : (Wr[(size_t)(k - K) * H_DIM + col] + Rw[(size_t)(k - K) * H_DIM + col]);
        o[e] = (short)f2bf(v);
    }
    *reinterpret_cast<short8*>(&out[(size_t)tid * 8]) = o;
}

// ---------------------------------------------------------------------------
// fused prep: cvt(x->bf16) | bias-combine+binCnt-zero | packw0 | packw1 | bounds
#define CVT_BLOCKS   3125
#define PW0_BLOCKS   8
#define PW1_BLOCKS   16
#define BND_BLOCKS   196
__launch_bounds__(256)
__global__ void prep_kernel(const float* __restrict__ x, u16* __restrict__ xbf,
                            const float* __restrict__ l0b, const float* __restrict__ r0b,
                            const float* __restrict__ l1b, const float* __restrict__ r1b,
                            float* __restrict__ bcc, int* __restrict__ binCnt,
                            const float* __restrict__ Wl0, const float* __restrict__ Wr0,
                            const float* __restrict__ Rw0, u16* __restrict__ W0p,
                            const float* __restrict__ Wl1, const float* __restrict__ Wr1,
                            const float* __restrict__ Rw1, u16* __restrict__ W1p,
                            const int* __restrict__ batch, int* __restrict__ gstart) {
    const int b = blockIdx.x;
    const int tid = threadIdx.x;
    if (b < CVT_BLOCKS) {
        int i = b * 256 + tid;
        float4 v = reinterpret_cast<const float4*>(x)[i];
        ushort4 o;
        o.x = f2bf(v.x); o.y = f2bf(v.y); o.z = f2bf(v.z); o.w = f2bf(v.w);
        reinterpret_cast<ushort4*>(xbf)[i] = o;
    } else if (b == CVT_BLOCKS) {
        if (tid < 128) {
            bcc[tid]       = l0b[tid] + r0b[tid];
            bcc[128 + tid] = l1b[tid] + r1b[tid];
            binCnt[tid] = 0;
            binCnt[128 + tid] = 0;
        }
    } else if (b < CVT_BLOCKS + 1 + PW0_BLOCKS) {
        packw_body(Wl0, Wr0, Rw0, W0p, F_IN, (b - CVT_BLOCKS - 1) * 256 + tid);
    } else if (b < CVT_BLOCKS + 1 + PW0_BLOCKS + PW1_BLOCKS) {
        packw_body(Wl1, Wr1, Rw1, W1p, H_DIM, (b - CVT_BLOCKS - 1 - PW0_BLOCKS) * 256 + tid);
    } else {
        int i = (b - CVT_BLOCKS - 1 - PW0_BLOCKS - PW1_BLOCKS) * 256 + tid;
        if (i >= N_NODES) return;
        int bb = batch[i];
        int prev = (i == 0) ? -1 : batch[i - 1];
        for (int g = prev + 1; g <= bb; ++g) gstart[g] = i;
        if (i == N_NODES - 1)
            for (int g = bb + 1; g <= N_GRAPHS; ++g) gstart[g] = N_NODES;
    }
}

// ---------------------------------------------------------------------------
// Phase 1: partition edges into NBINS coarse bins (bin = dst>>8).
#define EPT (CHUNK / 256)
__launch_bounds__(256)
__global__ void partition_kernel(const int* __restrict__ src, const int* __restrict__ dst,
                                 int* __restrict__ binCnt, ushort2* __restrict__ binned) {
    __shared__ ushort2 lbuf[CHUNK];
    __shared__ int sHist[256];
    __shared__ int sScan[256];
    __shared__ int sCur[256];
    __shared__ int sGBase[256];
    __shared__ int sWS[4];
    const int tid = threadIdx.x;
    const int base = blockIdx.x * CHUNK;
    const int cnt = min(CHUNK, N_EDGES - base);

    int es[EPT], ed[EPT], nb[EPT];
    #pragma unroll
    for (int i = 0; i < EPT; ++i) {
        int idx = base + i * 256 + tid;
        if (idx < N_EDGES) { es[i] = src[idx]; ed[i] = dst[idx]; nb[i] = ed[i] >> 8; }
        else nb[i] = -1;
    }
    sHist[tid] = 0;
    __syncthreads();
    #pragma unroll
    for (int i = 0; i < EPT; ++i) if (nb[i] >= 0) atomicAdd(&sHist[nb[i]], 1);
    __syncthreads();

    int v = sHist[tid];
    int pv = v;
    #pragma unroll
    for (int off = 1; off < 64; off <<= 1) {
        int t = __shfl_up(pv, off, 64);
        if ((tid & 63) >= off) pv += t;
    }
    if ((tid & 63) == 63) sWS[tid >> 6] = pv;
    __syncthreads();
    int wadd = 0;
    #pragma unroll
    for (int wg = 0; wg < 4; ++wg) if (wg < (tid >> 6)) wadd += sWS[wg];
    int excl = pv + wadd - v;
    sScan[tid] = excl;
    sCur[tid]  = excl;
    if (tid < NBINS && v > 0)
        sGBase[tid] = atomicAdd(&binCnt[tid], v);
    __syncthreads();

    #pragma unroll
    for (int i = 0; i < EPT; ++i) {
        if (nb[i] >= 0) {
            int p = atomicAdd(&sCur[nb[i]], 1);
            ushort2 t; t.x = (u16)es[i]; t.y = (u16)ed[i];
            lbuf[p] = t;
        }
    }
    __syncthreads();

    for (int t = tid; t < cnt; t += 256) {
        ushort2 e = lbuf[t];
        int b = e.y >> 8;
        int slot = sGBase[b] + (t - sScan[b]);
        if (slot < BINCAP) binned[(size_t)b * BINCAP + slot] = e;
    }
}

// ---------------------------------------------------------------------------
// Phase 2: per-bin bucket fill (u16 bucket); per-node cursors in LDS.
// 512 threads/block: 196 blocks was only 0.77 blocks/CU -- more waves per bin
// stream the bin's ~4096 edges with 2x memory parallelism.
__launch_bounds__(512)
__global__ void fillbin_kernel(const ushort2* __restrict__ binned, const int* __restrict__ binCnt,
                               u16* __restrict__ bucket, int* __restrict__ degv) {
    __shared__ int lcur[256];
    const int b = blockIdx.x;
    const int tid = threadIdx.x;
    const int nodeBase = b << 8;
    if (tid < 256) lcur[tid] = 0;
    __syncthreads();
    int cnt = binCnt[b];
    if (cnt > BINCAP) cnt = BINCAP;
    const ushort2* be = &binned[(size_t)b * BINCAP];
    for (int t = tid; t < cnt; t += 512) {
        ushort2 e = be[t];
        int d = e.y;
        int pos = atomicAdd(&lcur[d & 255], 1);
        if (pos < CAP) bucket[(size_t)d * CAP + pos] = e.x;
    }
    __syncthreads();
    if (tid < 256) {
        int node = nodeBase + tid;
        if (node < N_NODES) degv[node] = lcur[tid];
    }
}

// ---------------------------------------------------------------------------
// gather-aggregate: 16-deep ILP (16 outstanding row loads/wave), SGPR row bases
// via readfirstlane on packed u16 index pairs. One wave per node (TLP is the
// latency-hiding mechanism here -- do NOT serialize multiple nodes per wave,
// round-10 fusion tried that and regressed 36%).
template <int K>
__launch_bounds__(256)
__global__ void gather_kernel(const u16* __restrict__ h, const u16* __restrict__ bucket,
                              const int* __restrict__ degv, u16* __restrict__ agg) {
    const int node = (blockIdx.x * blockDim.x + threadIdx.x) >> 6;
    const int lane = threadIdx.x & 63;
    if (node >= N_NODES) return;
    int dg = degv[node];
    int dgc = dg > CAP ? CAP : dg;
    const u16* bk = &bucket[(size_t)node * CAP];
    const int lane2 = lane * 2;

    float a0[8], a1[8];
    #pragma unroll
    for (int u = 0; u < 8; ++u) { a0[u] = 0.f; a1[u] = 0.f; }

    int e = 0;
    // ---- 16-edge main loop: 16 loads in flight ----
    for (; e + 16 <= dgc; e += 16) {
        int4 qa = *reinterpret_cast<const int4*>(&bk[e]);        // 8 u16 idx
        int4 qb = *reinterpret_cast<const int4*>(&bk[e + 8]);    // 8 u16 idx
        u32 p[8];
        p[0] = (u32)__builtin_amdgcn_readfirstlane(qa.x);
        p[1] = (u32)__builtin_amdgcn_readfirstlane(qa.y);
        p[2] = (u32)__builtin_amdgcn_readfirstlane(qa.z);
        p[3] = (u32)__builtin_amdgcn_readfirstlane(qa.w);
        p[4] = (u32)__builtin_amdgcn_readfirstlane(qb.x);
        p[5] = (u32)__builtin_amdgcn_readfirstlane(qb.y);
        p[6] = (u32)__builtin_amdgcn_readfirstlane(qb.z);
        p[7] = (u32)__builtin_amdgcn_readfirstlane(qb.w);
        if constexpr (K == 128) {
            u32 w[16];
            #pragma unroll
            for (int u = 0; u < 8; ++u) {
                w[2 * u]     = *reinterpret_cast<const u32*>(h + (size_t)(p[u] & 0xFFFFu) * K + lane2);
                w[2 * u + 1] = *reinterpret_cast<const u32*>(h + (size_t)(p[u] >> 16) * K + lane2);
            }
            #pragma unroll
            for (int u = 0; u < 8; ++u) {
                a0[u] += bf2f((u16)w[u]);        a1[u] += bf2f((u16)(w[u] >> 16));
                a0[u] += bf2f((u16)w[u + 8]);    a1[u] += bf2f((u16)(w[u + 8] >> 16));
            }
        } else {
            u16 w[16];
            #pragma unroll
            for (int u = 0; u < 8; ++u) {
                w[2 * u]     = *(h + (size_t)(p[u] & 0xFFFFu) * K + lane);
                w[2 * u + 1] = *(h + (size_t)(p[u] >> 16) * K + lane);
            }
            #pragma unroll
            for (int u = 0; u < 8; ++u) { a0[u] += bf2f(w[u]); a0[u] += bf2f(w[u + 8]); }
        }
    }
    // ---- 8-edge loop ----
    for (; e + 8 <= dgc; e += 8) {
        int4 qa = *reinterpret_cast<const int4*>(&bk[e]);
        u32 p[4];
        p[0] = (u32)__builtin_amdgcn_readfirstlane(qa.x);
        p[1] = (u32)__builtin_amdgcn_readfirstlane(qa.y);
        p[2] = (u32)__builtin_amdgcn_readfirstlane(qa.z);
        p[3] = (u32)__builtin_amdgcn_readfirstlane(qa.w);
        if constexpr (K == 128) {
            u32 w[8];
            #pragma unroll
            for (int u = 0; u < 4; ++u) {
                w[2 * u]     = *reinterpret_cast<const u32*>(h + (size_t)(p[u] & 0xFFFFu) * K + lane2);
                w[2 * u + 1] = *reinterpret_cast<const u32*>(h + (size_t)(p[u] >> 16) * K + lane2);
            }
            #pragma unroll
            for (int u = 0; u < 8; ++u) { a0[u] += bf2f((u16)w[u]); a1[u] += bf2f((u16)(w[u] >> 16)); }
        } else {
            u16 w[8];
            #pragma unroll
            for (int u = 0; u < 4; ++u) {
                w[2 * u]     = *(h + (size_t)(p[u] & 0xFFFFu) * K + lane);
                w[2 * u + 1] = *(h + (size_t)(p[u] >> 16) * K + lane);
            }
            #pragma unroll
            for (int u = 0; u < 8; ++u) a0[u] += bf2f(w[u]);
        }
    }
    // ---- tail: fixed accumulator slots, scalar idx ----
    {
        int rem = dgc - e;
        #pragma unroll
        for (int u = 0; u < 7; ++u) {
            if (u < rem) {
                int s = __builtin_amdgcn_readfirstlane((int)bk[e + u]);
                if constexpr (K == 128) {
                    u32 w = *reinterpret_cast<const u32*>(h + (size_t)s * K + lane2);
                    a0[u] += bf2f((u16)w);
                    a1[u] += bf2f((u16)(w >> 16));
                } else {
                    a0[u] += bf2f(*(h + (size_t)s * K + lane));
                }
            }
        }
    }
    const float invd = 1.0f / fmaxf((float)dg, 1.0f);
    const float s0 = (((a0[0] + a0[1]) + (a0[2] + a0[3])) + ((a0[4] + a0[5]) + (a0[6] + a0[7]))) * invd;
    if constexpr (K == 128) {
        const float s1 = (((a1[0] + a1[1]) + (a1[2] + a1[3])) + ((a1[4] + a1[5]) + (a1[6] + a1[7]))) * invd;
        u32 o = (u32)f2bf(s0) | ((u32)f2bf(s1) << 16);
        *reinterpret_cast<u32*>(&agg[(size_t)node * K + lane2]) = o;
    } else {
        agg[(size_t)node * K + lane] = f2bf(s0);
    }
}

// ---------------------------------------------------------------------------
// fused MFMA layer: pre = [agg | hin] @ [Wl ; Wc] + bc ; t = LN(pre)
template <int K, bool RELU, bool FINAL>
__launch_bounds__(256)
__global__ void layer_mfma_kernel(const u16* __restrict__ aggbf,
                                  const u16* __restrict__ hbf,
                                  const u16* __restrict__ Wpack,
                                  const float* __restrict__ bc,
                                  const float* __restrict__ ln_g,
                                  const float* __restrict__ ln_b,
                                  const float* __restrict__ ow,
                                  u16* __restrict__ hout,
                                  float* __restrict__ sout) {
    constexpr int K2   = 2 * K;
    constexpr int NKS  = K2 / 32;
    constexpr int ROWB = K2 * 2;
    constexpr int CPR  = ROWB / 16;
    __shared__ __align__(16) char sA[64 * ROWB];

    const int tid  = threadIdx.x;
    const int lane = tid & 63;
    const int wid  = tid >> 6;
    const int base = blockIdx.x * 64;

    for (int c = tid; c < 64 * CPR; c += 256) {
        int row = c / CPR, c16 = c % CPR;
        int rg = base + row; if (rg >= N_NODES) rg = N_NODES - 1;
        const u16* srcp = (c16 < CPR / 2) ? &aggbf[(size_t)rg * K + c16 * 8]
                                          : &hbf[(size_t)rg * K + (c16 - CPR / 2) * 8];
        float4 v = *reinterpret_cast<const float4*>(srcp);
        *reinterpret_cast<float4*>(&sA[row * ROWB + ((c16 * 16) ^ ((row & 7) << 4))]) = v;
    }
    __syncthreads();

    f32x4 acc[8];
    #pragma unroll
    for (int t = 0; t < 8; ++t) acc[t] = (f32x4){0.f, 0.f, 0.f, 0.f};

    const int arow = lane & 15;
    const int kg   = lane >> 4;
    const int lrow = wid * 16 + arow;
    #pragma unroll
    for (int ks = 0; ks < NKS; ++ks) {
        short8 af = *reinterpret_cast<const short8*>(
            &sA[lrow * ROWB + (((ks * 64 + kg * 16)) ^ ((lrow & 7) << 4))]);
        #pragma unroll
        for (int t = 0; t < 8; ++t) {
            short8 bf = *reinterpret_cast<const short8*>(&Wpack[(size_t)((ks * 8 + t) * 64 + lane) * 8]);
            acc[t] = __builtin_amdgcn_mfma_f32_16x16x32_bf16(af, bf, acc[t], 0, 0, 0);
        }
    }

    const int col0 = lane & 15;
    const int g    = lane >> 4;

    float lg[8], lb[8], wv[8];
    #pragma unroll
    for (int t = 0; t < 8; ++t) {
        const int col = col0 + 16 * t;
        const float cb = bc[col];
        lg[t] = ln_g[col]; lb[t] = ln_b[col];
        if (FINAL) wv[t] = ow[col];
        #pragma unroll
        for (int r = 0; r < 4; ++r) acc[t][r] += cb;
    }

    #pragma unroll
    for (int r = 0; r < 4; ++r) {
        float s = 0.f, q = 0.f;
        #pragma unroll
        for (int t = 0; t < 8; ++t) { s += acc[t][r]; q += acc[t][r] * acc[t][r]; }
        #pragma unroll
        for (int off = 8; off > 0; off >>= 1) {
            s += __shfl_xor(s, off, 64);
            q += __shfl_xor(q, off, 64);
        }
        const float mean = s * (1.0f / H_DIM);
        const float var  = q * (1.0f / H_DIM) - mean * mean;
        const float rstd = rsqrtf(var + LN_EPS);
        const int row = base + wid * 16 + g * 4 + r;

        if (FINAL) {
            float dot = 0.f;
            #pragma unroll
            for (int t = 0; t < 8; ++t) {
                float o = (acc[t][r] - mean) * rstd * lg[t] + lb[t];
                dot += o * wv[t];
            }
            #pragma unroll
            for (int off = 8; off > 0; off >>= 1) dot += __shfl_xor(dot, off, 64);
            if (col0 == 0 && row < N_NODES) sout[row] = dot;
        } else {
            if (row < N_NODES) {
                #pragma unroll
                for (int t = 0; t < 8; ++t) {
                    float o = (acc[t][r] - mean) * rstd * lg[t] + lb[t];
                    if (RELU) o = fmaxf(o, 0.f);
                    hout[(size_t)row * H_DIM + col0 + 16 * t] = f2bf(o);
                }
            }
        }
    }
}

// ---------------------------------------------------------------------------
__device__ __forceinline__ float waveReduceSum(float v) {
    #pragma unroll
    for (int off = 32; off > 0; off >>= 1) v += __shfl_xor(v, off, 64);
    return v;
}

__global__ void graph_mean_kernel(const float* __restrict__ s, const int* __restrict__ start,
                                  const float* __restrict__ ob, float* __restrict__ out) {
    const int g = blockIdx.x;
    const int lane = threadIdx.x;
    const int a = start[g], b = start[g + 1];
    float sum = 0.f;
    for (int i = a + lane; i < b; i += 64) sum += s[i];
    sum = waveReduceSum(sum);
    if (lane == 0) out[g] = sum / fmaxf((float)(b - a), 1.0f) + ob[0];
}

// ---------------------------------------------------------------------------
static inline size_t align256(size_t x) { return (x + 255) & ~(size_t)255; }

extern "C" void kernel_launch(void* const* d_in, const int* in_sizes, int n_in,
                              void* d_out, int out_size, void* d_ws, size_t ws_size,
                              hipStream_t stream) {
    const float* x        = (const float*)d_in[0];
    const int*   eidx     = (const int*)d_in[1];
    const int*   batch    = (const int*)d_in[2];
    const float* lin_l0_w = (const float*)d_in[3];
    const float* lin_l0_b = (const float*)d_in[4];
    const float* lin_r0_w = (const float*)d_in[5];
    const float* res0_w   = (const float*)d_in[6];
    const float* res0_b   = (const float*)d_in[7];
    const float* ln0_g    = (const float*)d_in[8];
    const float* ln0_b    = (const float*)d_in[9];
    const float* lin_l1_w = (const float*)d_in[10];
    const float* lin_l1_b = (const float*)d_in[11];
    const float* lin_r1_w = (const float*)d_in[12];
    const float* res1_w   = (const float*)d_in[13];
    const float* res1_b   = (const float*)d_in[14];
    const float* ln1_g    = (const float*)d_in[15];
    const float* ln1_b    = (const float*)d_in[16];
    const float* out_w    = (const float*)d_in[17];
    const float* out_b    = (const float*)d_in[18];
    float* out = (float*)d_out;

    const int* src = eidx;
    const int* dst = eidx + N_EDGES;

    // workspace layout
    char* p = (char*)d_ws;
    int*     binCnt = (int*)p;     p += align256(256 * 4);
    ushort2* binned = (ushort2*)p; p += align256((size_t)NBINS * BINCAP * 4);
    int*     degv   = (int*)p;     p += align256((size_t)N_NODES * 4);
    u16*     bucket = (u16*)p;     p += align256((size_t)N_NODES * CAP * 2);
    int*     gstart = (int*)p;     p += align256((size_t)(N_GRAPHS + 1) * 4);
    u16*     xbf    = (u16*)p;     p += align256((size_t)N_NODES * F_IN * 2);
    u16*     h0bf   = (u16*)p;     p += align256((size_t)N_NODES * H_DIM * 2);
    u16*     aggbf  = (u16*)p;     p += align256((size_t)N_NODES * H_DIM * 2);
    float*   snode  = (float*)p;   p += align256((size_t)N_NODES * 4);
    u16*     W0p    = (u16*)p;     p += align256((size_t)(2 * F_IN) * H_DIM * 2);
    u16*     W1p    = (u16*)p;     p += align256((size_t)(2 * H_DIM) * H_DIM * 2);
    float*   bcc    = (float*)p;   p += align256(256 * 4);

    // fused prep (cvt + bias/binCnt + packw0 + packw1 + bounds)
    prep_kernel<<<CVT_BLOCKS + 1 + PW0_BLOCKS + PW1_BLOCKS + BND_BLOCKS, 256, 0, stream>>>(
        x, xbf, lin_l0_b, res0_b, lin_l1_b, res1_b, bcc, binCnt,
        lin_l0_w, lin_r0_w, res0_w, W0p, lin_l1_w, lin_r1_w, res1_w, W1p,
        batch, gstart);

    // two-phase edge bucketing
    partition_kernel<<<(N_EDGES + CHUNK - 1) / CHUNK, 256, 0, stream>>>(src, dst, binCnt, binned);
    fillbin_kernel<<<NBINS, 512, 0, stream>>>(binned, binCnt, bucket, degv);

    const int nTiles = (N_NODES + 63) / 64;

    // layer 0
    gather_kernel<F_IN><<<(N_NODES * 64 + 255) / 256, 256, 0, stream>>>(xbf, bucket, degv, aggbf);
    layer_mfma_kernel<F_IN, true, false><<<nTiles, 256, 0, stream>>>(
        aggbf, xbf, W0p, bcc, ln0_g, ln0_b, nullptr, h0bf, nullptr);

    // layer 1 (fused with out_w dot -> per-node scalar)
    gather_kernel<H_DIM><<<(N_NODES * 64 + 255) / 256, 256, 0, stream>>>(h0bf, bucket, degv, aggbf);
    layer_mfma_kernel<H_DIM, false, true><<<nTiles, 256, 0, stream>>>(
        aggbf, h0bf, W1p, bcc + 128, ln1_g, ln1_b, out_w, nullptr, snode);

    // per-graph mean + bias
    graph_mean_kernel<<<N_GRAPHS, 64, 0, stream>>>(snode, gstart, out_b, out);
}